// Round 8
// baseline (155.569 us; speedup 1.0000x reference)
//
#include <hip/hip_runtime.h>
#include <hip/hip_bf16.h>

#define NR  8192      // rows per view
#define M   16384     // 2*NR concatenated
#define DIM 128

constexpr float INV_T   = 2.5f;                  // 1/0.4
constexpr float SCALE_S = 1.89914134f;           // sqrt(2.5*log2(e)); s^2=2.5*log2e
constexpr float E_REFL  = 12.182493960703473f;   // exp(2.5)

typedef short short8 __attribute__((ext_vector_type(8)));
typedef float f32x4  __attribute__((ext_vector_type(4)));

__device__ __forceinline__ unsigned short f2bf(float f) {
    __hip_bfloat16 h = __float2bfloat16(f);
    return *reinterpret_cast<unsigned short*>(&h);
}

__device__ __forceinline__ float fexp2(float x) {
#if __has_builtin(__builtin_amdgcn_exp2f)
    return __builtin_amdgcn_exp2f(x);
#else
    return exp2f(x);
#endif
}

// ---------------------------------------------------------------------------
// Kernel 1: L2-normalize rows; store bf16 Z = [z1n; z2n] PRE-SCALED by
// SCALE_S (MFMA output is then directly the exp2 argument); fp32 cross dot;
// zero the rowsum array R.
// ---------------------------------------------------------------------------
__global__ __launch_bounds__(256) void norm_kernel(
    const float* __restrict__ outp, const float* __restrict__ augp,
    unsigned short* __restrict__ Z, float* __restrict__ R,
    float* __restrict__ posdot)
{
    int gt = blockIdx.x * 256 + threadIdx.x;
    if (gt < M) R[gt] = 0.0f;

    const int w    = threadIdx.x >> 6;
    const int lane = threadIdx.x & 63;
    const int row  = blockIdx.x * 4 + w;

    float2 a = *(const float2*)(outp + row * DIM + lane * 2);
    float2 b = *(const float2*)(augp + row * DIM + lane * 2);

    float ssa = a.x * a.x + a.y * a.y;
    float ssb = b.x * b.x + b.y * b.y;
    #pragma unroll
    for (int m = 1; m < 64; m <<= 1) {
        ssa += __shfl_xor(ssa, m);
        ssb += __shfl_xor(ssb, m);
    }
    float inva = 1.0f / fmaxf(sqrtf(ssa), 1e-12f);
    float invb = 1.0f / fmaxf(sqrtf(ssb), 1e-12f);

    float xa0 = a.x * inva, xa1 = a.y * inva;
    float xb0 = b.x * invb, xb1 = b.y * invb;

    ushort2 s1; s1.x = f2bf(xa0 * SCALE_S); s1.y = f2bf(xa1 * SCALE_S);
    ushort2 s2; s2.x = f2bf(xb0 * SCALE_S); s2.y = f2bf(xb1 * SCALE_S);
    *(ushort2*)(Z + (size_t)row * DIM + lane * 2)        = s1;
    *(ushort2*)(Z + (size_t)(NR + row) * DIM + lane * 2) = s2;

    float d = xa0 * xb0 + xa1 * xb1;
    #pragma unroll
    for (int m = 1; m < 64; m <<= 1) d += __shfl_xor(d, m);
    if (lane == 0) posdot[row] = d;
}

// ---------------------------------------------------------------------------
// Kernel 2: row sums of exp2(Zs Zs^T) — ZERO LDS, ZERO BARRIERS.
// All fragments (A and B) are read directly global->registers from the
// L2-resident Z (4 MB total; per-XCD Y working set ~1 MB under the implicit
// id%8 = ch%8 chunk->XCD pinning).  Waves run completely independently, so
// MFMA / VALU(exp2) / VMEM pipes of co-resident waves overlap naturally —
// no phase-locking, no barrier drain, no LDS bank conflicts.
// Grid (32 col-chunks, 64 row-blocks) = 2048 blocks (~8/CU of work, smooth
// tail).  Block = 256 thr / 4 waves owns 256 rows; wave owns 64 rows
// (afrag[4][4] regs).  Y chunk = 512 cols = 8 subtiles of 64 rows; per ct
// (16 cols): 4 x global_load_dwordx4 (software-pipelined one ct ahead into
// a named double buffer, rule-20-safe) -> 16 MFMA -> 16 exp2 -> accumulate.
// B-read amplification (each wave reads full subtile): 4x -> ~18 TB/s
// aggregate L2 read, ~50% of ceiling, ~2.2 TB/s per XCD.
// ---------------------------------------------------------------------------
__global__ __launch_bounds__(256, 3) void gram_kernel(
    const unsigned short* __restrict__ Z, float* __restrict__ R)
{
    const int tid  = threadIdx.x;
    const int w    = tid >> 6;       // 0..3
    const int lane = tid & 63;
    const int l16  = lane & 15;
    const int lg   = lane >> 4;      // 0..3 (k-group)
    const int ch   = blockIdx.x;     // 0..31 (512 cols each)
    const int rb   = blockIdx.y;     // 0..63 (256 rows each)

    const char* Zb = (const char*)Z;
    const char* Xg = Zb + (size_t)rb * 65536;     // 256 rows * 256 B
    const char* Yg = Zb + (size_t)ch * 131072;    // 512 cols * 256 B

    // A fragments: 64 rows per wave, 4 k-slices, direct from global (one-time)
    short8 afrag[4][4];
    #pragma unroll
    for (int rt = 0; rt < 4; ++rt)
        #pragma unroll
        for (int ks = 0; ks < 4; ++ks)
            afrag[rt][ks] = *(const short8*)(
                Xg + (w * 64 + rt * 16 + l16) * 256 + ks * 64 + lg * 16);

    f32x4 rs[4];
    #pragma unroll
    for (int rt = 0; rt < 4; ++rt) rs[rt] = (f32x4){0.f, 0.f, 0.f, 0.f};
    const f32x4 zero4 = (f32x4){0.f, 0.f, 0.f, 0.f};

    // lane-base for B-fragment reads: row_local = ct*16+l16, k-chunk = lg
    const char* yb = Yg + l16 * 256 + lg * 16;

    auto compute = [&](short8 b0, short8 b1, short8 b2, short8 b3) {
        #pragma unroll
        for (int rt = 0; rt < 4; ++rt) {
            f32x4 a;
            a = __builtin_amdgcn_mfma_f32_16x16x32_bf16(afrag[rt][0], b0, zero4, 0, 0, 0);
            a = __builtin_amdgcn_mfma_f32_16x16x32_bf16(afrag[rt][1], b1, a, 0, 0, 0);
            a = __builtin_amdgcn_mfma_f32_16x16x32_bf16(afrag[rt][2], b2, a, 0, 0, 0);
            a = __builtin_amdgcn_mfma_f32_16x16x32_bf16(afrag[rt][3], b3, a, 0, 0, 0);
            f32x4 e;
            e[0] = fexp2(a[0]); e[1] = fexp2(a[1]);
            e[2] = fexp2(a[2]); e[3] = fexp2(a[3]);
            rs[rt] += e;
        }
    };

#define LOADF(d0, d1, d2, d3, off)                       \
    d0 = *(const short8*)(yb + (off));                   \
    d1 = *(const short8*)(yb + (off) + 64);              \
    d2 = *(const short8*)(yb + (off) + 128);             \
    d3 = *(const short8*)(yb + (off) + 192);

    short8 c0, c1, c2, c3, p0, p1, p2, p3;
    LOADF(c0, c1, c2, c3, 0)                 // (s=0, ct=0)

    int base = 0;                            // byte offset of subtile s
    #pragma unroll 1
    for (int s = 0; s < 8; ++s) {
        // ct parity walk: c,p,c,p ; prefetch one ct ahead
        LOADF(p0, p1, p2, p3, base + 4096)   // ct=1
        compute(c0, c1, c2, c3);             // ct=0
        LOADF(c0, c1, c2, c3, base + 8192)   // ct=2
        compute(p0, p1, p2, p3);             // ct=1
        LOADF(p0, p1, p2, p3, base + 12288)  // ct=3
        compute(c0, c1, c2, c3);             // ct=2
        {   // prefetch next subtile's ct=0 (wrap to 0 on last — harmless)
            int nb = (s + 1 < 8) ? base + 16384 : 0;
            LOADF(c0, c1, c2, c3, nb)
        }
        compute(p0, p1, p2, p3);             // ct=3
        base += 16384;
    }
#undef LOADF

    // reduce row sums across the 16 lanes holding one row's columns
    #pragma unroll
    for (int rt = 0; rt < 4; ++rt)
        #pragma unroll
        for (int q = 0; q < 4; ++q) {
            float v = rs[rt][q];
            v += __shfl_xor(v, 1);  v += __shfl_xor(v, 2);
            v += __shfl_xor(v, 4);  v += __shfl_xor(v, 8);
            if (l16 == 0)
                atomicAdd(&R[rb * 256 + w * 64 + rt * 16 + lg * 4 + q], v);
        }
}

// ---------------------------------------------------------------------------
// Kernel 3: loss = mean_i [ -dot_i/tau + 0.5(log(R_i - E) + log(R_{NR+i} - E)) ]
// ---------------------------------------------------------------------------
__global__ __launch_bounds__(256) void final_kernel(
    const float* __restrict__ R, const float* __restrict__ posdot,
    float* __restrict__ outv)
{
    float local = 0.0f;
    for (int i = threadIdx.x; i < NR; i += 256) {
        float d1 = R[i]      - E_REFL;
        float d2 = R[NR + i] - E_REFL;
        local += -posdot[i] * INV_T + 0.5f * (logf(d1) + logf(d2));
    }
    __shared__ float red[256];
    red[threadIdx.x] = local;
    __syncthreads();
    for (int s = 128; s > 0; s >>= 1) {
        if ((int)threadIdx.x < s) red[threadIdx.x] += red[threadIdx.x + s];
        __syncthreads();
    }
    if (threadIdx.x == 0) outv[0] = red[0] * (1.0f / NR);
}

// ---------------------------------------------------------------------------
extern "C" void kernel_launch(void* const* d_in, const int* in_sizes, int n_in,
                              void* d_out, int out_size, void* d_ws, size_t ws_size,
                              hipStream_t stream) {
    const float* outp = (const float*)d_in[0];
    const float* augp = (const float*)d_in[1];

    char* ws = (char*)d_ws;
    unsigned short* Z = (unsigned short*)ws;                  // 4 MB bf16 [16384][128]
    float* R      = (float*)(ws + 4194304);                   // 16384 f32 row sums
    float* posdot = (float*)(ws + 4194304 + 65536);           // 8192 f32
    float* outf   = (float*)d_out;

    hipLaunchKernelGGL(norm_kernel, dim3(2048), dim3(256), 0, stream,
                       outp, augp, Z, R, posdot);

    hipLaunchKernelGGL(gram_kernel, dim3(32, 64), dim3(256), 0, stream,
                       Z, R);

    hipLaunchKernelGGL(final_kernel, dim3(1), dim3(256), 0, stream,
                       R, posdot, outf);
}

// Round 9
// 63.116 us; speedup vs baseline: 2.4648x; 2.4648x over previous
//
#include <hip/hip_runtime.h>
#include <hip/hip_bf16.h>

#define NR  8192      // rows per view
#define M   16384     // 2*NR concatenated
#define SUBB 8192     // 64 cols * 128 B (one fp8 Y sub-tile)

constexpr float INV_T   = 2.5f;                  // 1/0.4
constexpr float SCALE_S = 1.89914134f;           // sqrt(2.5*log2(e)); s^2=2.5*log2e
constexpr float E_REFL  = 12.182493960703473f;   // exp(2.5)
constexpr unsigned UNIT_E8M0 = 0x7F7F7F7Fu;      // e8m0 scale = 2^0 in all bytes

typedef int   i32x4 __attribute__((ext_vector_type(4)));
typedef int   i32x8 __attribute__((ext_vector_type(8)));
typedef float f32x4 __attribute__((ext_vector_type(4)));

typedef const __attribute__((address_space(1))) unsigned int* gas_u32;
typedef __attribute__((address_space(3))) unsigned int*       las_u32;

__device__ __forceinline__ float fexp2(float x) {
#if __has_builtin(__builtin_amdgcn_exp2f)
    return __builtin_amdgcn_exp2f(x);
#else
    return exp2f(x);
#endif
}

// Stage one 64-col (8 KB) fp8 sub-tile global->LDS with 256 threads:
// 2 x global_load_lds(16B) per thread. LDS dest linear (wave-uniform base,
// HW adds lane*16); global src XOR-pre-swizzled (involution on byte bits
// 4..6 keyed by row&7 = bits 7..9) so swizzled 16B fragment reads are
// low-conflict (2-way max).
__device__ __forceinline__ void stage_sub8(const char* __restrict__ gsrc,
                                           char* lds, int w, int lane) {
    #pragma unroll
    for (int it = 0; it < 2; ++it) {
        int off = w * 2048 + it * 1024 + lane * 16;
        int swz = off ^ (((off >> 7) & 7) << 4);
        __builtin_amdgcn_global_load_lds((gas_u32)(gsrc + swz),
                                         (las_u32)(lds + w * 2048 + it * 1024),
                                         16, 0, 0);
    }
}

// ---------------------------------------------------------------------------
// Kernel 1: L2-normalize rows; store fp8(e4m3) Z = [z1n; z2n] PRE-SCALED by
// SCALE_S (so the MX-MFMA output is directly the exp2 argument); fp32 cross
// dot; zero the rowsum array R.
// ---------------------------------------------------------------------------
__global__ __launch_bounds__(256) void norm_kernel(
    const float* __restrict__ outp, const float* __restrict__ augp,
    unsigned char* __restrict__ Zf8, float* __restrict__ R,
    float* __restrict__ posdot)
{
    int gt = blockIdx.x * 256 + threadIdx.x;
    if (gt < M) R[gt] = 0.0f;

    const int w    = threadIdx.x >> 6;
    const int lane = threadIdx.x & 63;
    const int row  = blockIdx.x * 4 + w;

    float2 a = *(const float2*)(outp + row * 128 + lane * 2);
    float2 b = *(const float2*)(augp + row * 128 + lane * 2);

    float ssa = a.x * a.x + a.y * a.y;
    float ssb = b.x * b.x + b.y * b.y;
    #pragma unroll
    for (int m = 1; m < 64; m <<= 1) {
        ssa += __shfl_xor(ssa, m);
        ssb += __shfl_xor(ssb, m);
    }
    float inva = 1.0f / fmaxf(sqrtf(ssa), 1e-12f);
    float invb = 1.0f / fmaxf(sqrtf(ssb), 1e-12f);

    float xa0 = a.x * inva, xa1 = a.y * inva;   // unit-normalized (fp32)
    float xb0 = b.x * invb, xb1 = b.y * invb;

    // fp8 e4m3 pack of prescaled values (2 per thread -> 2 bytes)
    unsigned int pa = __builtin_amdgcn_cvt_pk_fp8_f32(xa0 * SCALE_S, xa1 * SCALE_S, 0, false);
    unsigned int pb = __builtin_amdgcn_cvt_pk_fp8_f32(xb0 * SCALE_S, xb1 * SCALE_S, 0, false);
    *(unsigned short*)(Zf8 + (size_t)row * 128 + lane * 2)        = (unsigned short)pa;
    *(unsigned short*)(Zf8 + (size_t)(NR + row) * 128 + lane * 2) = (unsigned short)pb;

    float d = xa0 * xb0 + xa1 * xb1;   // positive-pair dot stays fp32-exact
    #pragma unroll
    for (int m = 1; m < 64; m <<= 1) d += __shfl_xor(d, m);
    if (lane == 0) posdot[row] = d;
}

// ---------------------------------------------------------------------------
// Kernel 2: row sums of exp2(Zs Zs^T) via MX-fp8 K=128 MFMA.
// One mfma_scale_f32_16x16x128_f8f6f4 (unit e8m0 scales, fmt 0 = fp8 e4m3)
// covers the ENTIRE K per 16x16 output tile: 2.25x bf16 MFMA rate, and fp8
// halves LDS traffic.  Grid (16 col-chunks, 64 row-blocks) = 1024 blocks
// = 4/CU (launch_bounds(256,4); 16 KB LDS).  Block = 256 thr / 4 waves owns
// 256 rows; wave owns 64 rows: afrag[4] (8 VGPR each, 32B = full K) read
// once, direct from global (L2-resident: per-XCD set = 2 MB A + 256 KB Y
// under the id%8 chunk pinning).  Y chunk = 1024 cols = 16 subtiles of 64
// cols (8 KB), double-buffered via global_load_lds.  Per ct (16 cols):
// 2 swizzled 16B LDS reads -> b8 operand -> 4 MFMA (rt) -> 16 exp2 -> 16
// adds; trans-pipe exp2 (13.6 us/CU floor) overlaps the MFMA pipe
// (14.7 us/CU floor) across the 16 resident waves.
// A/B fragment layout (mirrors 16x16x32 bf16, verified m148 port): lane l
// holds row/col l&15, k-bytes (l>>4)*32 .. +32.  C/D: col=lane&15,
// row=(lane>>4)*4+reg.
// ---------------------------------------------------------------------------
__global__ __launch_bounds__(256, 4) void gram_kernel(
    const unsigned char* __restrict__ Zf8, float* __restrict__ R)
{
    __shared__ char buf[2][SUBB];   // 16 KB

    const int tid  = threadIdx.x;
    const int w    = tid >> 6;       // 0..3
    const int lane = tid & 63;
    const int l16  = lane & 15;
    const int lg   = lane >> 4;      // 0..3 (32-byte k-chunk)
    const int ch   = blockIdx.x;     // 0..15 (1024 cols each)
    const int rb   = blockIdx.y;     // 0..63 (256 rows each)

    const char* Zb = (const char*)Zf8;
    const char* Xg = Zb + (size_t)rb * 32768;     // 256 rows * 128 B
    const char* Yg = Zb + (size_t)ch * 131072;    // 1024 cols * 128 B

    // A fragments: 64 rows per wave, full K=128 (32 B/lane), one-time read
    i32x8 afrag[4];
    #pragma unroll
    for (int rt = 0; rt < 4; ++rt)
        afrag[rt] = *(const i32x8*)(Xg + (w * 64 + rt * 16 + l16) * 128 + lg * 32);

    stage_sub8(Yg, buf[0], w, lane);
    __syncthreads();

    f32x4 rs[4];
    #pragma unroll
    for (int rt = 0; rt < 4; ++rt) rs[rt] = (f32x4){0.f, 0.f, 0.f, 0.f};
    const f32x4 zero4 = (f32x4){0.f, 0.f, 0.f, 0.f};

    #pragma unroll 1
    for (int s = 0; s < 16; ++s) {
        if (s + 1 < 16)
            stage_sub8(Yg + (size_t)(s + 1) * SUBB, buf[(s + 1) & 1], w, lane);

        const char* cur = buf[s & 1];

        #pragma unroll
        for (int ct = 0; ct < 4; ++ct) {
            int row  = ct * 16 + l16;
            int base = row * 128 + lg * 32;
            int key  = (row & 7) << 4;
            i32x4 lo = *(const i32x4*)(cur + (base ^ key));
            i32x4 hi = *(const i32x4*)(cur + ((base + 16) ^ key));
            i32x8 b8 = {lo[0], lo[1], lo[2], lo[3], hi[0], hi[1], hi[2], hi[3]};
            #pragma unroll
            for (int rt = 0; rt < 4; ++rt) {
                f32x4 d = __builtin_amdgcn_mfma_scale_f32_16x16x128_f8f6f4(
                    afrag[rt], b8, zero4,
                    0 /*fmtA=fp8*/, 0 /*fmtB=fp8*/,
                    0, UNIT_E8M0, 0, UNIT_E8M0);
                f32x4 e;
                e[0] = fexp2(d[0]); e[1] = fexp2(d[1]);
                e[2] = fexp2(d[2]); e[3] = fexp2(d[3]);
                rs[rt] += e;
            }
        }
        __syncthreads();   // stage(s+1) landed + all waves done with cur
    }

    // reduce row sums across the 16 lanes holding one row's columns
    #pragma unroll
    for (int rt = 0; rt < 4; ++rt)
        #pragma unroll
        for (int q = 0; q < 4; ++q) {
            float v = rs[rt][q];
            v += __shfl_xor(v, 1);  v += __shfl_xor(v, 2);
            v += __shfl_xor(v, 4);  v += __shfl_xor(v, 8);
            if (l16 == 0)
                atomicAdd(&R[rb * 256 + w * 64 + rt * 16 + lg * 4 + q], v);
        }
}

// ---------------------------------------------------------------------------
// Kernel 3: loss = mean_i [ -dot_i/tau + 0.5(log(R_i - E) + log(R_{NR+i} - E)) ]
// ---------------------------------------------------------------------------
__global__ __launch_bounds__(256) void final_kernel(
    const float* __restrict__ R, const float* __restrict__ posdot,
    float* __restrict__ outv)
{
    float local = 0.0f;
    for (int i = threadIdx.x; i < NR; i += 256) {
        float d1 = R[i]      - E_REFL;
        float d2 = R[NR + i] - E_REFL;
        local += -posdot[i] * INV_T + 0.5f * (logf(d1) + logf(d2));
    }
    __shared__ float red[256];
    red[threadIdx.x] = local;
    __syncthreads();
    for (int s = 128; s > 0; s >>= 1) {
        if ((int)threadIdx.x < s) red[threadIdx.x] += red[threadIdx.x + s];
        __syncthreads();
    }
    if (threadIdx.x == 0) outv[0] = red[0] * (1.0f / NR);
}

// ---------------------------------------------------------------------------
extern "C" void kernel_launch(void* const* d_in, const int* in_sizes, int n_in,
                              void* d_out, int out_size, void* d_ws, size_t ws_size,
                              hipStream_t stream) {
    const float* outp = (const float*)d_in[0];
    const float* augp = (const float*)d_in[1];

    char* ws = (char*)d_ws;
    unsigned char* Zf8 = (unsigned char*)ws;                  // 2 MB fp8 [16384][128]
    float* R      = (float*)(ws + 2097152);                   // 16384 f32 row sums
    float* posdot = (float*)(ws + 2097152 + 65536);           // 8192 f32
    float* outf   = (float*)d_out;

    hipLaunchKernelGGL(norm_kernel, dim3(2048), dim3(256), 0, stream,
                       outp, augp, Zf8, R, posdot);

    hipLaunchKernelGGL(gram_kernel, dim3(16, 64), dim3(256), 0, stream,
                       Zf8, R);

    hipLaunchKernelGGL(final_kernel, dim3(1), dim3(256), 0, stream,
                       R, posdot, outf);
}